// Round 4
// baseline (1503.936 us; speedup 1.0000x reference)
//
#include <hip/hip_runtime.h>
#include <hip/hip_bf16.h>
#include <math.h>

#define D_MODEL 1024
#define SLOTS   4096
#define LEVELS  3
#define BT      16384   // B*T = 4*4096
#define HDIM    512
#define NCAND   16
#define TOPK    8

// i8 quantization scales:
// q ~ N(0,1): clip +-5.08 sigma (scale 25); K ~ U(+-0.03424): scale 3700 never clips.
// per-score approx error sigma ~= 2.4e-4 (i8) + 7.8e-5 (K i8) + 3e-5 (fp16 store).
#define QSCALE 25.0f
#define KSCALE 3700.0f
// membership ambiguity margin: >=7 sigma of pairwise approx error
#define DELTA  2.5e-3f

typedef float    f32x4  __attribute__((ext_vector_type(4)));
typedef int      i32x4  __attribute__((ext_vector_type(4)));
typedef __bf16   bf16x8 __attribute__((ext_vector_type(8)));
typedef _Float16 f16x8  __attribute__((ext_vector_type(8)));

// async global->LDS, 16B per lane. LDS dest is wave-uniform base + lane*16.
__device__ __forceinline__ void gl_lds16(const void* g, void* l) {
  __builtin_amdgcn_global_load_lds((const __attribute__((address_space(1))) void*)g,
                                   (__attribute__((address_space(3))) void*)l, 16, 0, 0);
}

// ---------- fp helpers ----------
__device__ __forceinline__ unsigned short f2bf(float f) {
  union { float f; unsigned u; } v; v.f = f;
  unsigned r = (v.u + 0x7fffu + ((v.u >> 16) & 1u)) >> 16;
  return (unsigned short)r;
}
__device__ __forceinline__ float bf2f(unsigned short b) {
  union { unsigned u; float f; } v; v.u = ((unsigned)b) << 16; return v.f;
}
__device__ __forceinline__ unsigned short f2h_bits(float f) {
  union { _Float16 h; unsigned short u; } v; v.h = (_Float16)f; return v.u;
}
__device__ __forceinline__ float h2f(unsigned short b) {
  union { unsigned short u; _Float16 h; } v; v.u = b; return (float)v.h;
}
__device__ __forceinline__ int q_i8(float f, float scale) {
  float v = f * scale;
  v = fminf(fmaxf(v, -127.0f), 127.0f);
  return (int)rintf(v);
}
__device__ __forceinline__ unsigned umaxu(unsigned a, unsigned b) { return a > b ? a : b; }
__device__ __forceinline__ unsigned uminu(unsigned a, unsigned b) { return a < b ? a : b; }

// ---------- conversion kernels ----------
__global__ __launch_bounds__(256) void conv_i8_kernel(const float* __restrict__ src,
                                                      char* __restrict__ dst, float scale) {
  int i = blockIdx.x * 256 + threadIdx.x;          // 16-elem index
  const float4* s = (const float4*)src + i * 4;
  int w[4];
#pragma unroll
  for (int g = 0; g < 4; ++g) {
    float4 v = s[g];
    int b0 = q_i8(v.x, scale) & 255, b1 = q_i8(v.y, scale) & 255;
    int b2 = q_i8(v.z, scale) & 255, b3 = q_i8(v.w, scale) & 255;
    w[g] = b0 | (b1 << 8) | (b2 << 16) | (b3 << 24);
  }
  ((int4*)dst)[i] = make_int4(w[0], w[1], w[2], w[3]);
}

// fused: q -> i8 (for scores GEMM) AND bf16-hi (for router A operand)
__global__ __launch_bounds__(256) void conv_q8h_kernel(const float* __restrict__ q,
                                                       char* __restrict__ q8,
                                                       unsigned short* __restrict__ qh) {
  int i = blockIdx.x * 256 + threadIdx.x;          // 16-elem index
  const float4* s = (const float4*)q + i * 4;
  int w[4]; unsigned hh[8];
#pragma unroll
  for (int g = 0; g < 4; ++g) {
    float4 v = s[g];
    int b0 = q_i8(v.x, QSCALE) & 255, b1 = q_i8(v.y, QSCALE) & 255;
    int b2 = q_i8(v.z, QSCALE) & 255, b3 = q_i8(v.w, QSCALE) & 255;
    w[g] = b0 | (b1 << 8) | (b2 << 16) | (b3 << 24);
    hh[g * 2 + 0] = (unsigned)f2bf(v.x) | ((unsigned)f2bf(v.y) << 16);
    hh[g * 2 + 1] = (unsigned)f2bf(v.z) | ((unsigned)f2bf(v.w) << 16);
  }
  ((int4*)q8)[i] = make_int4(w[0], w[1], w[2], w[3]);
  uint4* qp = (uint4*)qh + i * 2;
  qp[0] = make_uint4(hh[0], hh[1], hh[2], hh[3]);
  qp[1] = make_uint4(hh[4], hh[5], hh[6], hh[7]);
}

__global__ __launch_bounds__(256) void conv_w1t_kernel(const float* __restrict__ W1,
                                                       unsigned short* __restrict__ Wh,
                                                       unsigned short* __restrict__ Wl) {
  int e = blockIdx.x * 256 + threadIdx.x;          // e = k*512 + n
  int k = e >> 9, n = e & 511;
  float f = W1[e];
  unsigned short hb = f2bf(f);
  Wh[(size_t)n * 1024 + k] = hb;
  Wl[(size_t)n * 1024 + k] = f2bf(f - bf2f(hb));
}

// V -> fp16 for the final gather (halves gather bytes; err <= 1.5e-5, negligible)
__global__ __launch_bounds__(256) void conv_v16_kernel(const float* __restrict__ Vs,
                                                       _Float16* __restrict__ V16) {
  int i = blockIdx.x * 256 + threadIdx.x;          // 8-elem index
  const float4* s = (const float4*)Vs + i * 2;
  float4 a = s[0], b = s[1];
  f16x8 o;
  o[0] = (_Float16)a.x; o[1] = (_Float16)a.y; o[2] = (_Float16)a.z; o[3] = (_Float16)a.w;
  o[4] = (_Float16)b.x; o[5] = (_Float16)b.y; o[6] = (_Float16)b.z; o[7] = (_Float16)b.w;
  ((f16x8*)V16)[i] = o;
}

__global__ void init_counters_kernel(int* __restrict__ c) { c[threadIdx.x] = 0; }

// ---------- scores GEMM (i8): C[m,s] = fp16((q8.K8)*dq + sal[s]) ----------
__global__ __launch_bounds__(256) void gemm_scores_i8_kernel(
    const char* __restrict__ A,   // [rows][1024] i8 (chunk base pre-applied)
    const char* __restrict__ B,   // [4096][1024] i8 (level's K)
    const float* __restrict__ sal,
    unsigned short* __restrict__ C) {   // [chunk][4096] fp16
  __shared__ __align__(16) char As[128 * 64];
  __shared__ __align__(16) char Bs[128 * 64];
  const int tid = threadIdx.x;
  const int bx = blockIdx.x, by = blockIdx.y;
  const int lane = tid & 63, wave = tid >> 6;
  const int wm = wave >> 1, wn = wave & 1;

  const char* gA = A + (size_t)(by * 128 + (tid >> 2)) * 1024 + (tid & 3) * 16;
  const char* gB = B + (size_t)(bx * 128 + (tid >> 2)) * 1024 + (tid & 3) * 16;
  char* lA = As + tid * 16;
  char* lB = Bs + tid * 16;

  i32x4 acc[4][4] = {};

  for (int k0 = 0; k0 < 1024; k0 += 64) {
    __syncthreads();
    gl_lds16(gA + k0,             lA);
    gl_lds16(gA + 64 * 1024 + k0, lA + 64 * 64);
    gl_lds16(gB + k0,             lB);
    gl_lds16(gB + 64 * 1024 + k0, lB + 64 * 64);
    __syncthreads();

    const int fr = lane & 15, fk = (lane >> 4) * 16;
    i32x4 a[4], b[4];
#pragma unroll
    for (int i = 0; i < 4; ++i) a[i] = *(const i32x4*)(As + (wm * 64 + i * 16 + fr) * 64 + fk);
#pragma unroll
    for (int j = 0; j < 4; ++j) b[j] = *(const i32x4*)(Bs + (wn * 64 + j * 16 + fr) * 64 + fk);
#pragma unroll
    for (int i = 0; i < 4; ++i)
#pragma unroll
      for (int j = 0; j < 4; ++j)
        acc[i][j] = __builtin_amdgcn_mfma_i32_16x16x64_i8(a[i], b[j], acc[i][j], 0, 0, 0);
  }

  const float dq = 1.0f / (QSCALE * KSCALE * 32.0f);
  const int rr = (lane >> 4) * 4, cc = lane & 15;
#pragma unroll
  for (int i = 0; i < 4; ++i)
#pragma unroll
    for (int j = 0; j < 4; ++j) {
      int col = bx * 128 + wn * 64 + j * 16 + cc;
      float s = sal[col];
      int rowb = by * 128 + wm * 64 + i * 16 + rr;
#pragma unroll
      for (int r = 0; r < 4; ++r)
        C[(size_t)(rowb + r) * 4096 + col] = f2h_bits((float)acc[i][j][r] * dq + s);
    }
}

// ---------- router GEMM: h = relu(q @ W1 + b1) ----------
__global__ __launch_bounds__(256) void gemm_router_kernel(
    const unsigned short* __restrict__ Ah,
    const unsigned short* __restrict__ Bh, const unsigned short* __restrict__ Bl,
    const float* __restrict__ b1, float* __restrict__ H) {
  __shared__ __align__(16) unsigned short Ash[128 * 32];
  __shared__ __align__(16) unsigned short Bsh[128 * 32], Bsl[128 * 32];
  const int tid = threadIdx.x;
  const int bx = blockIdx.x, by = blockIdx.y;
  const int lane = tid & 63, wave = tid >> 6;
  const int wm = wave >> 1, wn = wave & 1;

  const int s_row = wave * 16 + (lane >> 2);
  const int s_c8  = (lane & 3) * 8;
  const unsigned short* gAh = Ah + (size_t)(by * 128 + s_row) * 1024 + s_c8;
  const unsigned short* gBh = Bh + (size_t)(bx * 128 + s_row) * 1024 + s_c8;
  const unsigned short* gBl = Bl + (size_t)(bx * 128 + s_row) * 1024 + s_c8;
  unsigned short* lAh = Ash + s_row * 32 + s_c8;
  unsigned short* lBh = Bsh + s_row * 32 + s_c8;
  unsigned short* lBl = Bsl + s_row * 32 + s_c8;

  f32x4 acc[4][4] = {};

  for (int k0 = 0; k0 < 1024; k0 += 32) {
    __syncthreads();
    gl_lds16(gAh + k0,             lAh);
    gl_lds16(gAh + 64 * 1024 + k0, lAh + 64 * 32);
    gl_lds16(gBh + k0,             lBh);
    gl_lds16(gBh + 64 * 1024 + k0, lBh + 64 * 32);
    gl_lds16(gBl + k0,             lBl);
    gl_lds16(gBl + 64 * 1024 + k0, lBl + 64 * 32);
    __syncthreads();

    const int fr = lane & 15, fk = (lane >> 4) * 8;
    bf16x8 ah[4], bh[4], bl[4];
#pragma unroll
    for (int i = 0; i < 4; ++i) {
      int off = (wm * 64 + i * 16 + fr) * 32 + fk;
      ah[i] = *(const bf16x8*)(Ash + off);
    }
#pragma unroll
    for (int j = 0; j < 4; ++j) {
      int off = (wn * 64 + j * 16 + fr) * 32 + fk;
      bh[j] = *(const bf16x8*)(Bsh + off);
      bl[j] = *(const bf16x8*)(Bsl + off);
    }
#pragma unroll
    for (int i = 0; i < 4; ++i)
#pragma unroll
      for (int j = 0; j < 4; ++j) {
        acc[i][j] = __builtin_amdgcn_mfma_f32_16x16x32_bf16(ah[i], bh[j], acc[i][j], 0, 0, 0);
        acc[i][j] = __builtin_amdgcn_mfma_f32_16x16x32_bf16(ah[i], bl[j], acc[i][j], 0, 0, 0);
      }
  }

  const int rr = (lane >> 4) * 4, cc = lane & 15;
#pragma unroll
  for (int i = 0; i < 4; ++i)
#pragma unroll
    for (int j = 0; j < 4; ++j) {
      int col = bx * 128 + wn * 64 + j * 16 + cc;
      float bias = b1[col];
      int rowb = by * 128 + wm * 64 + i * 16 + rr;
#pragma unroll
      for (int r = 0; r < 4; ++r) {
        float v = acc[i][j][r] + bias;
        H[(size_t)(rowb + r) * HDIM + col] = v > 0.0f ? v : 0.0f;
      }
    }
}

// ---------- router head ----------
__global__ __launch_bounds__(256) void router_head_kernel(
    const float* __restrict__ H, const float* __restrict__ W2,
    const float* __restrict__ b2, float* __restrict__ route_w) {
  int wave = threadIdx.x >> 6, lane = threadIdx.x & 63;
  int row = blockIdx.x * 4 + wave;
  float a0 = 0.f, a1 = 0.f, a2 = 0.f;
#pragma unroll
  for (int k = 0; k < 8; ++k) {
    int d = k * 64 + lane;
    float hv = H[(size_t)row * HDIM + d];
    a0 += hv * W2[d * 3 + 0];
    a1 += hv * W2[d * 3 + 1];
    a2 += hv * W2[d * 3 + 2];
  }
#pragma unroll
  for (int m = 1; m < 64; m <<= 1) {
    a0 += __shfl_xor(a0, m); a1 += __shfl_xor(a1, m); a2 += __shfl_xor(a2, m);
  }
  if (lane == 0) {
    float l0 = a0 + b2[0], l1 = a1 + b2[1], l2 = a2 + b2[2];
    float mx = fmaxf(l0, fmaxf(l1, l2));
    float e0 = expf(l0 - mx), e1 = expf(l1 - mx), e2 = expf(l2 - mx);
    float inv = 1.0f / (e0 + e1 + e2);
    route_w[(size_t)row * 3 + 0] = e0 * inv;
    route_w[(size_t)row * 3 + 1] = e1 * inv;
    route_w[(size_t)row * 3 + 2] = e2 * inv;
  }
}

// ---------- select: ONE WAVE per row, top-16 of 4096 fp16 scores (register-only) ----------
// Kept minimal (VGPR ~36): writes cand2 only. Classification lives in classify_kernel —
// fusing it here in round 3 pushed register pressure past the allocator's choice (44 VGPR)
// and spilled av/idx/ew to scratch: VALUBusy 101%->24%, dur 24->216us.
template<bool FILTER>
__device__ __forceinline__ void top4_build(const uint4 (&v)[8], unsigned lane8, unsigned bound,
                                           unsigned &t0, unsigned &t1, unsigned &t2, unsigned &t3) {
  t0 = t1 = t2 = t3 = 0u;
#pragma unroll
  for (int i = 0; i < 8; ++i) {
    unsigned wds[4] = {v[i].x, v[i].y, v[i].z, v[i].w};
#pragma unroll
    for (int g = 0; g < 4; ++g) {
      unsigned w = wds[g];
      unsigned s = w & 0x80008000u;
      // per-half: key16 = v ^ (sign ? 0xFFFF : 0x8000); packed in one u32 (IEEE sign-mag)
      unsigned key2 = (w ^ 0x80008000u) ^ (s - (s >> 15));
      unsigned pb = lane8 + (unsigned)(i * 512 + g * 2);
      unsigned kA = (key2 << 16) | pb;                 // low half element
      unsigned kB = (key2 & 0xFFFF0000u) | (pb + 1u);  // high half element
      if (FILTER) {
        if (kA >= bound) kA = 0u;
        if (kB >= bound) kB = 0u;
      }
      unsigned x, y, z;
      x = uminu(t0, kA); t0 = umaxu(t0, kA);
      y = uminu(t1, x);  t1 = umaxu(t1, x);
      z = uminu(t2, y);  t2 = umaxu(t2, y);
      t3 = umaxu(t3, z);
      x = uminu(t0, kB); t0 = umaxu(t0, kB);
      y = uminu(t1, x);  t1 = umaxu(t1, x);
      z = uminu(t2, y);  t2 = umaxu(t2, y);
      t3 = umaxu(t3, z);
    }
  }
}

__global__ __launch_bounds__(256) void select_kernel(
    const unsigned short* __restrict__ S,    // [chunk][4096] fp16
    int2* __restrict__ cand2, int c0, int level) {
  int wave = threadIdx.x >> 6, lane = threadIdx.x & 63;
  int rlocal = blockIdx.x * 4 + wave;
  const uint4* row = (const uint4*)(S + (size_t)rlocal * 4096);  // 512 uint4/row

  uint4 v[8];
#pragma unroll
  for (int i = 0; i < 8; ++i) v[i] = row[i * 64 + lane];   // 1KB/wave/iter, coalesced

  const unsigned lane8 = (unsigned)lane * 8u;
  unsigned t0, t1, t2, t3;
  top4_build<false>(v, lane8, 0u, t0, t1, t2, t3);

  unsigned myres = 0u;
#pragma clang loop unroll(disable)
  for (int r = 0; r < NCAND; ++r) {
    unsigned g = t0;
#pragma unroll
    for (int m = 1; m < 64; m <<= 1) {
      unsigned o = (unsigned)__shfl_xor((int)g, m);
      g = umaxu(g, o);
    }
    if (t0 == g) {               // unique winner (pos embedded in key)
      t0 = t1; t1 = t2; t2 = t3; t3 = 0u;
      if (t0 == 0u)              // list exhausted: exact rebuild of remaining
        top4_build<true>(v, lane8, g, t0, t1, t2, t3);
    }
    if (lane == r) myres = g;
  }

  size_t base = ((size_t)(c0 + rlocal) * 3 + level) * NCAND;
  if (lane < NCAND) {
    unsigned k16 = myres >> 16;
    unsigned ob = k16 ^ ((k16 & 0x8000u) ? 0x8000u : 0xFFFFu);  // undo key transform
    cand2[base + lane] = make_int2((int)(myres & 0xFFFFu),
                                   __float_as_int(h2f((unsigned short)ob)));
  }
}

// ---------- classify: one wave per row; easy rows finalized, hard rows -> worklist ----------
// Tiny dedicated kernel so av[]/idx[]/ew[] live comfortably in registers (rescore-like
// footprint, ~60-80 VGPR, no spill).
__global__ __launch_bounds__(256) void classify_kernel(
    const int2* __restrict__ cand2, const float* __restrict__ route_w,
    int2* __restrict__ worklist, int* __restrict__ counter, int slot,
    int* __restrict__ sel_idx, float* __restrict__ sel_w,
    int c0, int level) {
  const int wave = threadIdx.x >> 6, lane = threadIdx.x & 63;
  const int row = c0 + blockIdx.x * 4 + wave;
  const size_t cb = ((size_t)row * 3 + level) * NCAND;

  // lane j (mod 16) holds candidate j; coalesced 8B loads
  int2 pr = cand2[cb + (lane & 15)];
  float my_av = __int_as_float(pr.y);

  // broadcast all 16 (score,idx) to every lane (static shuffle indices)
  float av[NCAND]; int idx[NCAND];
#pragma unroll
  for (int j = 0; j < NCAND; ++j) {
    av[j]  = __shfl(my_av, j);
    idx[j] = __shfl(pr.x, j);
  }

  // lane i<16 classifies candidate i; masks assembled via ballot
  int cnt_hi = 0, cnt_lo = 0;
  const int me = lane & 15;
#pragma unroll
  for (int j = 0; j < NCAND; ++j) {
    cnt_hi += (av[j] > my_av + DELTA) ? 1 : 0;
    cnt_lo += (j != me && av[j] > my_av - DELTA) ? 1 : 0;
  }
  bool is_out = (cnt_hi >= TOPK);
  bool is_cin = !is_out && (cnt_lo <= TOPK - 1);
  bool is_amb = !is_out && !is_cin;
  unsigned long long cb_cin = __ballot(lane < 16 && is_cin);
  unsigned long long cb_amb = __ballot(lane < 16 && is_amb);
  const int cin_mask = (int)(cb_cin & 0xFFFFu);
  const int amb_mask = (int)(cb_amb & 0xFFFFu);

  const int need = TOPK - __popc((unsigned)cin_mask);
  const bool hard = (need > 0) && (__popc((unsigned)amb_mask) > need);

  if (hard) {
    if (lane == 0) {
      int e = atomicAdd(counter + slot, 1);
      worklist[e] = make_int2(row, cin_mask | (amb_mask << 16));
    }
    return;
  }

  // easy: selection fully determined (popc(amb)==need when need>0)
  const int selm = (need > 0) ? (cin_mask | amb_mask) : cin_mask;
  float mx = -INFINITY;
#pragma unroll
  for (int j = 0; j < NCAND; ++j)
    if ((selm >> j) & 1) mx = fmaxf(mx, av[j]);
  float ew[NCAND]; float sum = 0.f;
#pragma unroll
  for (int j = 0; j < NCAND; ++j) {
    ew[j] = 0.f;
    if ((selm >> j) & 1) { ew[j] = expf(av[j] - mx); sum += ew[j]; }
  }
  if (lane == 0) {
    float rw = route_w[(size_t)row * 3 + level] / sum;
    size_t b8 = ((size_t)row * 3 + level) * TOPK;
    int k = 0;
#pragma unroll
    for (int j = 0; j < NCAND; ++j)
      if ((selm >> j) & 1) {
        sel_idx[b8 + k] = idx[j];
        sel_w[b8 + k]  = ew[j] * rw;
        ++k;
      }
  }
}

// ---------- rescore: one wave per hard row from the worklist; fp64 exact dots ----------
__global__ __launch_bounds__(256) void rescore_kernel(
    const float* __restrict__ q, const float* __restrict__ Kl,
    const float* __restrict__ sal, const float* __restrict__ route_w,
    const int2* __restrict__ cand2,
    const int2* __restrict__ worklist, const int* __restrict__ counter, int slot,
    int level, int* __restrict__ sel_idx, float* __restrict__ sel_w) {
  const int wid  = blockIdx.x * 4 + (threadIdx.x >> 6);
  const int lane = threadIdx.x & 63;
  const int n = counter[slot];
  if (wid >= n) return;

  const int2 e = worklist[wid];
  const int row = e.x;
  const int cin_mask = e.y & 0xFFFF;
  const int amb_mask = (e.y >> 16) & 0xFFFF;
  const int need = TOPK - __popc((unsigned)cin_mask);

  float av[NCAND]; int idx[NCAND];
  {
    size_t cb = ((size_t)row * 3 + level) * NCAND;
#pragma unroll
    for (int c = 0; c < NCAND; ++c) {
      int2 pr = cand2[cb + c];
      idx[c] = pr.x; av[c] = __int_as_float(pr.y);
    }
  }

  // q row into regs (16 floats/lane, coalesced)
  float qr[16];
  {
    const float4* qp = (const float4*)(q + (size_t)row * 1024) + lane * 4;
#pragma unroll
    for (int m4 = 0; m4 < 4; ++m4) {
      float4 tv = qp[m4];
      qr[m4 * 4 + 0] = tv.x; qr[m4 * 4 + 1] = tv.y;
      qr[m4 * 4 + 2] = tv.z; qr[m4 * 4 + 3] = tv.w;
    }
  }

  double ex[NCAND];
#pragma unroll
  for (int c = 0; c < NCAND; ++c) {
    if (!((amb_mask >> c) & 1)) continue;
    int sx = idx[c];
    const float4* kr = (const float4*)(Kl + (size_t)sx * 1024) + lane * 4;
    double acc = 0.0;
#pragma unroll
    for (int m4 = 0; m4 < 4; ++m4) {
      float4 kv = kr[m4];
      acc = fma((double)qr[m4 * 4 + 0], (double)kv.x, acc);
      acc = fma((double)qr[m4 * 4 + 1], (double)kv.y, acc);
      acc = fma((double)qr[m4 * 4 + 2], (double)kv.z, acc);
      acc = fma((double)qr[m4 * 4 + 3], (double)kv.w, acc);
    }
#pragma unroll
    for (int m = 1; m < 64; m <<= 1) acc += __shfl_xor(acc, m);
    ex[c] = acc * 0.03125 + (double)sal[sx];
  }

  // selected mask: certain-in plus the 'need' best ambiguous by exact score
  int selm = cin_mask;
  unsigned rem = (unsigned)amb_mask;
  for (int p = 0; p < need; ++p) {
    double bs = -1e300; int bc = 0;
#pragma unroll
    for (int c = 0; c < NCAND; ++c)
      if ((rem >> c) & 1)
        if (ex[c] > bs) { bs = ex[c]; bc = c; }
    rem &= ~(1u << bc);
    selm |= (1 << bc);
  }

  // weights: softmax over approx scores of the selected 8, fold route weight
  float mx = -INFINITY;
#pragma unroll
  for (int j = 0; j < NCAND; ++j)
    if ((selm >> j) & 1) mx = fmaxf(mx, av[j]);
  float ew[NCAND]; float sum = 0.f;
#pragma unroll
  for (int j = 0; j < NCAND; ++j) {
    ew[j] = 0.f;
    if ((selm >> j) & 1) { ew[j] = expf(av[j] - mx); sum += ew[j]; }
  }
  if (lane == 0) {
    float rw = route_w[(size_t)row * 3 + level] / sum;
    size_t b8 = ((size_t)row * 3 + level) * TOPK;
    int k = 0;
#pragma unroll
    for (int j = 0; j < NCAND; ++j)
      if ((selm >> j) & 1) {
        sel_idx[b8 + k] = idx[j];
        sel_w[b8 + k]  = ew[j] * rw;
        ++k;
      }
  }
}

// ---------- final: out[row,:] = sum over 24 (level,k) of w * V16[level,idx,:] ----------
__global__ __launch_bounds__(128) void final_kernel(
    const _Float16* __restrict__ V16, const int* __restrict__ sel_idx,
    const float* __restrict__ sel_w, float* __restrict__ out) {
  __shared__ float wv[24];
  __shared__ int   widx[24];
  int row = blockIdx.x, t = threadIdx.x;   // t in [0,128): 8 halves each
  if (t < 24) {
    int l = t >> 3, j = t & 7;
    size_t base = ((size_t)row * 3 + l) * TOPK + j;
    wv[t]   = sel_w[base];
    widx[t] = l * SLOTS + sel_idx[base];
  }
  __syncthreads();
  float acc[8] = {0.f, 0.f, 0.f, 0.f, 0.f, 0.f, 0.f, 0.f};
  for (int i = 0; i < 24; ++i) {
    float w = wv[i];
    f16x8 v = *(const f16x8*)(V16 + (size_t)widx[i] * 1024 + t * 8);
#pragma unroll
    for (int e = 0; e < 8; ++e) acc[e] += w * (float)v[e];
  }
  float4* op = (float4*)(out + (size_t)row * 1024) + t * 2;
  op[0] = make_float4(acc[0], acc[1], acc[2], acc[3]);
  op[1] = make_float4(acc[4], acc[5], acc[6], acc[7]);
}

// ---------- launch ----------
extern "C" void kernel_launch(void* const* d_in, const int* in_sizes, int n_in,
                              void* d_out, int out_size, void* d_ws, size_t ws_size,
                              hipStream_t stream) {
  const float* q   = (const float*)d_in[0];
  const float* Ks  = (const float*)d_in[1];
  const float* Vs  = (const float*)d_in[2];
  const float* sal = (const float*)d_in[3];
  const float* W1  = (const float*)d_in[4];
  const float* b1  = (const float*)d_in[5];
  const float* W2  = (const float*)d_in[6];
  const float* b2  = (const float*)d_in[7];
  float* out = (float*)d_out;
  (void)in_sizes; (void)n_in; (void)out_size;

  char* p = (char*)d_ws;
  auto alloc = [&](size_t bytes) -> char* {
    char* r = p; p += (bytes + 255) & ~(size_t)255; return r;
  };
  // fixed (live across the whole pipeline)
  char*      q8    = alloc((size_t)BT * 1024);
  char*      K8    = alloc((size_t)LEVELS * SLOTS * 1024);
  _Float16*  V16   = (_Float16*)alloc((size_t)LEVELS * SLOTS * 1024 * 2);
  float*     route = (float*)alloc((size_t)BT * 3 * 4);
  int2*      cand2 = (int2*)alloc((size_t)BT * 3 * NCAND * 8);
  int*       s_idx = (int*)alloc((size_t)BT * 3 * TOPK * 4);
  float*     s_w   = (float*)alloc((size_t)BT * 3 * TOPK * 4);
  int*       ctrs  = (int*)alloc(32 * 4);
  int2*      wlist = (int2*)alloc((size_t)BT * 8);
  size_t fixed = (size_t)(p - (char*)d_ws);

  // aliased region: router temps (dead before scores loop) overlap scores buffer
  char* ali = p;
  unsigned short* qh   = (unsigned short*)alloc((size_t)BT * 1024 * 2);
  unsigned short* W1Th = (unsigned short*)alloc((size_t)HDIM * 1024 * 2);
  unsigned short* W1Tl = (unsigned short*)alloc((size_t)HDIM * 1024 * 2);
  float*          h    = (float*)alloc((size_t)BT * HDIM * 4);
  size_t router_bytes = (size_t)(p - ali);

  unsigned short* scores = (unsigned short*)ali;   // fp16 [chunk][4096]
  int chunk = 2048;
  const int opts[4] = {16384, 8192, 4096, 2048};
  for (int i = 0; i < 4; ++i) {
    size_t scores_b = (size_t)opts[i] * SLOTS * 2;
    size_t need = fixed + (scores_b > router_bytes ? scores_b : router_bytes);
    if (need <= ws_size) { chunk = opts[i]; break; }
  }

  // 0) counters
  init_counters_kernel<<<1, 32, 0, stream>>>(ctrs);

  // 1) conversions
  conv_q8h_kernel<<<(BT * 1024 / 16) / 256, 256, 0, stream>>>(q, q8, qh);
  conv_i8_kernel<<<(LEVELS * SLOTS * 1024 / 16) / 256, 256, 0, stream>>>(Ks, K8, KSCALE);
  conv_v16_kernel<<<(LEVELS * SLOTS * 1024 / 8) / 256, 256, 0, stream>>>(Vs, V16);
  conv_w1t_kernel<<<(1024 * HDIM) / 256, 256, 0, stream>>>(W1, W1Th, W1Tl);

  // 2) router
  gemm_router_kernel<<<dim3(HDIM / 128, BT / 128), 256, 0, stream>>>(qh, W1Th, W1Tl, b1, h);
  router_head_kernel<<<BT / 4, 256, 0, stream>>>(h, W2, b2, route);

  // 3) per level, per chunk: i8 scores -> top-16 -> classify (easy done) -> worklist rescore
  int slot = 0;
  for (int level = 0; level < LEVELS; ++level) {
    const char*  K8L  = K8 + (size_t)level * SLOTS * 1024;
    const float* salL = sal + (size_t)level * SLOTS;
    const float* KsL  = Ks + (size_t)level * SLOTS * 1024;
    for (int c0 = 0; c0 < BT; c0 += chunk, ++slot) {
      gemm_scores_i8_kernel<<<dim3(SLOTS / 128, chunk / 128), 256, 0, stream>>>(
          q8 + (size_t)c0 * 1024, K8L, salL, scores);
      select_kernel<<<chunk / 4, 256, 0, stream>>>(scores, cand2, c0, level);
      classify_kernel<<<chunk / 4, 256, 0, stream>>>(cand2, route, wlist, ctrs, slot,
                                                     s_idx, s_w, c0, level);
      rescore_kernel<<<chunk / 4, 256, 0, stream>>>(q, KsL, salL, route, cand2, wlist, ctrs, slot,
                                                    level, s_idx, s_w);
    }
  }

  // 4) gather + weighted sum
  final_kernel<<<BT, 128, 0, stream>>>(V16, s_idx, s_w, out);
}

// Round 5
// 1500.177 us; speedup vs baseline: 1.0025x; 1.0025x over previous
//
#include <hip/hip_runtime.h>
#include <hip/hip_bf16.h>
#include <math.h>

#define D_MODEL 1024
#define SLOTS   4096
#define LEVELS  3
#define BT      16384   // B*T = 4*4096
#define HDIM    512
#define NCAND   16
#define TOPK    8

// i8 quantization scales:
// q ~ N(0,1): clip +-5.08 sigma (scale 25); K ~ U(+-0.03424): scale 3700 never clips.
// per-score approx error sigma ~= 2.4e-4 (i8) + 7.8e-5 (K i8) + 3e-5 (fp16 store).
#define QSCALE 25.0f
#define KSCALE 3700.0f
// membership ambiguity margin: >=7 sigma of pairwise approx error
#define DELTA  2.5e-3f

typedef float    f32x4  __attribute__((ext_vector_type(4)));
typedef int      i32x4  __attribute__((ext_vector_type(4)));
typedef __bf16   bf16x8 __attribute__((ext_vector_type(8)));
typedef _Float16 f16x8  __attribute__((ext_vector_type(8)));

// async global->LDS, 16B per lane. LDS dest is wave-uniform base + lane*16.
__device__ __forceinline__ void gl_lds16(const void* g, void* l) {
  __builtin_amdgcn_global_load_lds((const __attribute__((address_space(1))) void*)g,
                                   (__attribute__((address_space(3))) void*)l, 16, 0, 0);
}

// ---------- fp helpers ----------
__device__ __forceinline__ unsigned short f2bf(float f) {
  union { float f; unsigned u; } v; v.f = f;
  unsigned r = (v.u + 0x7fffu + ((v.u >> 16) & 1u)) >> 16;
  return (unsigned short)r;
}
__device__ __forceinline__ float bf2f(unsigned short b) {
  union { unsigned u; float f; } v; v.u = ((unsigned)b) << 16; return v.f;
}
__device__ __forceinline__ unsigned short f2h_bits(float f) {
  union { _Float16 h; unsigned short u; } v; v.h = (_Float16)f; return v.u;
}
__device__ __forceinline__ float h2f(unsigned short b) {
  union { unsigned short u; _Float16 h; } v; v.u = b; return (float)v.h;
}
__device__ __forceinline__ int q_i8(float f, float scale) {
  float v = f * scale;
  v = fminf(fmaxf(v, -127.0f), 127.0f);
  return (int)rintf(v);
}
__device__ __forceinline__ unsigned umaxu(unsigned a, unsigned b) { return a > b ? a : b; }
__device__ __forceinline__ unsigned uminu(unsigned a, unsigned b) { return a < b ? a : b; }

// ---------- conversion kernels ----------
__global__ __launch_bounds__(256) void conv_i8_kernel(const float* __restrict__ src,
                                                      char* __restrict__ dst, float scale) {
  int i = blockIdx.x * 256 + threadIdx.x;          // 16-elem index
  const float4* s = (const float4*)src + i * 4;
  int w[4];
#pragma unroll
  for (int g = 0; g < 4; ++g) {
    float4 v = s[g];
    int b0 = q_i8(v.x, scale) & 255, b1 = q_i8(v.y, scale) & 255;
    int b2 = q_i8(v.z, scale) & 255, b3 = q_i8(v.w, scale) & 255;
    w[g] = b0 | (b1 << 8) | (b2 << 16) | (b3 << 24);
  }
  ((int4*)dst)[i] = make_int4(w[0], w[1], w[2], w[3]);
}

// fused: q -> i8 (for scores GEMM) AND bf16-hi (for router A operand)
__global__ __launch_bounds__(256) void conv_q8h_kernel(const float* __restrict__ q,
                                                       char* __restrict__ q8,
                                                       unsigned short* __restrict__ qh) {
  int i = blockIdx.x * 256 + threadIdx.x;          // 16-elem index
  const float4* s = (const float4*)q + i * 4;
  int w[4]; unsigned hh[8];
#pragma unroll
  for (int g = 0; g < 4; ++g) {
    float4 v = s[g];
    int b0 = q_i8(v.x, QSCALE) & 255, b1 = q_i8(v.y, QSCALE) & 255;
    int b2 = q_i8(v.z, QSCALE) & 255, b3 = q_i8(v.w, QSCALE) & 255;
    w[g] = b0 | (b1 << 8) | (b2 << 16) | (b3 << 24);
    hh[g * 2 + 0] = (unsigned)f2bf(v.x) | ((unsigned)f2bf(v.y) << 16);
    hh[g * 2 + 1] = (unsigned)f2bf(v.z) | ((unsigned)f2bf(v.w) << 16);
  }
  ((int4*)q8)[i] = make_int4(w[0], w[1], w[2], w[3]);
  uint4* qp = (uint4*)qh + i * 2;
  qp[0] = make_uint4(hh[0], hh[1], hh[2], hh[3]);
  qp[1] = make_uint4(hh[4], hh[5], hh[6], hh[7]);
}

__global__ __launch_bounds__(256) void conv_w1t_kernel(const float* __restrict__ W1,
                                                       unsigned short* __restrict__ Wh,
                                                       unsigned short* __restrict__ Wl) {
  int e = blockIdx.x * 256 + threadIdx.x;          // e = k*512 + n
  int k = e >> 9, n = e & 511;
  float f = W1[e];
  unsigned short hb = f2bf(f);
  Wh[(size_t)n * 1024 + k] = hb;
  Wl[(size_t)n * 1024 + k] = f2bf(f - bf2f(hb));
}

// V -> fp16 for the final gather (halves gather bytes; err <= 1.5e-5, negligible)
__global__ __launch_bounds__(256) void conv_v16_kernel(const float* __restrict__ Vs,
                                                       _Float16* __restrict__ V16) {
  int i = blockIdx.x * 256 + threadIdx.x;          // 8-elem index
  const float4* s = (const float4*)Vs + i * 2;
  float4 a = s[0], b = s[1];
  f16x8 o;
  o[0] = (_Float16)a.x; o[1] = (_Float16)a.y; o[2] = (_Float16)a.z; o[3] = (_Float16)a.w;
  o[4] = (_Float16)b.x; o[5] = (_Float16)b.y; o[6] = (_Float16)b.z; o[7] = (_Float16)b.w;
  ((f16x8*)V16)[i] = o;
}

__global__ void init_counters_kernel(int* __restrict__ c) { c[threadIdx.x] = 0; }

// ---------- scores GEMM (i8): C[m,s] = fp16((q8.K8)*dq + sal[s]) ----------
__global__ __launch_bounds__(256) void gemm_scores_i8_kernel(
    const char* __restrict__ A,   // [rows][1024] i8 (chunk base pre-applied)
    const char* __restrict__ B,   // [4096][1024] i8 (level's K)
    const float* __restrict__ sal,
    unsigned short* __restrict__ C) {   // [chunk][4096] fp16
  __shared__ __align__(16) char As[128 * 64];
  __shared__ __align__(16) char Bs[128 * 64];
  const int tid = threadIdx.x;
  const int bx = blockIdx.x, by = blockIdx.y;
  const int lane = tid & 63, wave = tid >> 6;
  const int wm = wave >> 1, wn = wave & 1;

  const char* gA = A + (size_t)(by * 128 + (tid >> 2)) * 1024 + (tid & 3) * 16;
  const char* gB = B + (size_t)(bx * 128 + (tid >> 2)) * 1024 + (tid & 3) * 16;
  char* lA = As + tid * 16;
  char* lB = Bs + tid * 16;

  i32x4 acc[4][4] = {};

  for (int k0 = 0; k0 < 1024; k0 += 64) {
    __syncthreads();
    gl_lds16(gA + k0,             lA);
    gl_lds16(gA + 64 * 1024 + k0, lA + 64 * 64);
    gl_lds16(gB + k0,             lB);
    gl_lds16(gB + 64 * 1024 + k0, lB + 64 * 64);
    __syncthreads();

    const int fr = lane & 15, fk = (lane >> 4) * 16;
    i32x4 a[4], b[4];
#pragma unroll
    for (int i = 0; i < 4; ++i) a[i] = *(const i32x4*)(As + (wm * 64 + i * 16 + fr) * 64 + fk);
#pragma unroll
    for (int j = 0; j < 4; ++j) b[j] = *(const i32x4*)(Bs + (wn * 64 + j * 16 + fr) * 64 + fk);
#pragma unroll
    for (int i = 0; i < 4; ++i)
#pragma unroll
      for (int j = 0; j < 4; ++j)
        acc[i][j] = __builtin_amdgcn_mfma_i32_16x16x64_i8(a[i], b[j], acc[i][j], 0, 0, 0);
  }

  const float dq = 1.0f / (QSCALE * KSCALE * 32.0f);
  const int rr = (lane >> 4) * 4, cc = lane & 15;
#pragma unroll
  for (int i = 0; i < 4; ++i)
#pragma unroll
    for (int j = 0; j < 4; ++j) {
      int col = bx * 128 + wn * 64 + j * 16 + cc;
      float s = sal[col];
      int rowb = by * 128 + wm * 64 + i * 16 + rr;
#pragma unroll
      for (int r = 0; r < 4; ++r)
        C[(size_t)(rowb + r) * 4096 + col] = f2h_bits((float)acc[i][j][r] * dq + s);
    }
}

// ---------- router GEMM: h = relu(q @ W1 + b1) ----------
__global__ __launch_bounds__(256) void gemm_router_kernel(
    const unsigned short* __restrict__ Ah,
    const unsigned short* __restrict__ Bh, const unsigned short* __restrict__ Bl,
    const float* __restrict__ b1, float* __restrict__ H) {
  __shared__ __align__(16) unsigned short Ash[128 * 32];
  __shared__ __align__(16) unsigned short Bsh[128 * 32], Bsl[128 * 32];
  const int tid = threadIdx.x;
  const int bx = blockIdx.x, by = blockIdx.y;
  const int lane = tid & 63, wave = tid >> 6;
  const int wm = wave >> 1, wn = wave & 1;

  const int s_row = wave * 16 + (lane >> 2);
  const int s_c8  = (lane & 3) * 8;
  const unsigned short* gAh = Ah + (size_t)(by * 128 + s_row) * 1024 + s_c8;
  const unsigned short* gBh = Bh + (size_t)(bx * 128 + s_row) * 1024 + s_c8;
  const unsigned short* gBl = Bl + (size_t)(bx * 128 + s_row) * 1024 + s_c8;
  unsigned short* lAh = Ash + s_row * 32 + s_c8;
  unsigned short* lBh = Bsh + s_row * 32 + s_c8;
  unsigned short* lBl = Bsl + s_row * 32 + s_c8;

  f32x4 acc[4][4] = {};

  for (int k0 = 0; k0 < 1024; k0 += 32) {
    __syncthreads();
    gl_lds16(gAh + k0,             lAh);
    gl_lds16(gAh + 64 * 1024 + k0, lAh + 64 * 32);
    gl_lds16(gBh + k0,             lBh);
    gl_lds16(gBh + 64 * 1024 + k0, lBh + 64 * 32);
    gl_lds16(gBl + k0,             lBl);
    gl_lds16(gBl + 64 * 1024 + k0, lBl + 64 * 32);
    __syncthreads();

    const int fr = lane & 15, fk = (lane >> 4) * 8;
    bf16x8 ah[4], bh[4], bl[4];
#pragma unroll
    for (int i = 0; i < 4; ++i) {
      int off = (wm * 64 + i * 16 + fr) * 32 + fk;
      ah[i] = *(const bf16x8*)(Ash + off);
    }
#pragma unroll
    for (int j = 0; j < 4; ++j) {
      int off = (wn * 64 + j * 16 + fr) * 32 + fk;
      bh[j] = *(const bf16x8*)(Bsh + off);
      bl[j] = *(const bf16x8*)(Bsl + off);
    }
#pragma unroll
    for (int i = 0; i < 4; ++i)
#pragma unroll
      for (int j = 0; j < 4; ++j) {
        acc[i][j] = __builtin_amdgcn_mfma_f32_16x16x32_bf16(ah[i], bh[j], acc[i][j], 0, 0, 0);
        acc[i][j] = __builtin_amdgcn_mfma_f32_16x16x32_bf16(ah[i], bl[j], acc[i][j], 0, 0, 0);
      }
  }

  const int rr = (lane >> 4) * 4, cc = lane & 15;
#pragma unroll
  for (int i = 0; i < 4; ++i)
#pragma unroll
    for (int j = 0; j < 4; ++j) {
      int col = bx * 128 + wn * 64 + j * 16 + cc;
      float bias = b1[col];
      int rowb = by * 128 + wm * 64 + i * 16 + rr;
#pragma unroll
      for (int r = 0; r < 4; ++r) {
        float v = acc[i][j][r] + bias;
        H[(size_t)(rowb + r) * HDIM + col] = v > 0.0f ? v : 0.0f;
      }
    }
}

// ---------- router head ----------
__global__ __launch_bounds__(256) void router_head_kernel(
    const float* __restrict__ H, const float* __restrict__ W2,
    const float* __restrict__ b2, float* __restrict__ route_w) {
  int wave = threadIdx.x >> 6, lane = threadIdx.x & 63;
  int row = blockIdx.x * 4 + wave;
  float a0 = 0.f, a1 = 0.f, a2 = 0.f;
#pragma unroll
  for (int k = 0; k < 8; ++k) {
    int d = k * 64 + lane;
    float hv = H[(size_t)row * HDIM + d];
    a0 += hv * W2[d * 3 + 0];
    a1 += hv * W2[d * 3 + 1];
    a2 += hv * W2[d * 3 + 2];
  }
#pragma unroll
  for (int m = 1; m < 64; m <<= 1) {
    a0 += __shfl_xor(a0, m); a1 += __shfl_xor(a1, m); a2 += __shfl_xor(a2, m);
  }
  if (lane == 0) {
    float l0 = a0 + b2[0], l1 = a1 + b2[1], l2 = a2 + b2[2];
    float mx = fmaxf(l0, fmaxf(l1, l2));
    float e0 = expf(l0 - mx), e1 = expf(l1 - mx), e2 = expf(l2 - mx);
    float inv = 1.0f / (e0 + e1 + e2);
    route_w[(size_t)row * 3 + 0] = e0 * inv;
    route_w[(size_t)row * 3 + 1] = e1 * inv;
    route_w[(size_t)row * 3 + 2] = e2 * inv;
  }
}

// ---------- select: ONE WAVE per row, top-16 of 4096 fp16 scores (register-only) ----------
template<bool FILTER>
__device__ __forceinline__ void top4_build(const uint4 (&v)[8], unsigned lane8, unsigned bound,
                                           unsigned &t0, unsigned &t1, unsigned &t2, unsigned &t3) {
  t0 = t1 = t2 = t3 = 0u;
#pragma unroll
  for (int i = 0; i < 8; ++i) {
    unsigned wds[4] = {v[i].x, v[i].y, v[i].z, v[i].w};
#pragma unroll
    for (int g = 0; g < 4; ++g) {
      unsigned w = wds[g];
      unsigned s = w & 0x80008000u;
      // per-half: key16 = v ^ (sign ? 0xFFFF : 0x8000); packed in one u32 (IEEE sign-mag)
      unsigned key2 = (w ^ 0x80008000u) ^ (s - (s >> 15));
      unsigned pb = lane8 + (unsigned)(i * 512 + g * 2);
      unsigned kA = (key2 << 16) | pb;                 // low half element
      unsigned kB = (key2 & 0xFFFF0000u) | (pb + 1u);  // high half element
      if (FILTER) {
        if (kA >= bound) kA = 0u;
        if (kB >= bound) kB = 0u;
      }
      unsigned x, y, z;
      x = uminu(t0, kA); t0 = umaxu(t0, kA);
      y = uminu(t1, x);  t1 = umaxu(t1, x);
      z = uminu(t2, y);  t2 = umaxu(t2, y);
      t3 = umaxu(t3, z);
      x = uminu(t0, kB); t0 = umaxu(t0, kB);
      y = uminu(t1, x);  t1 = umaxu(t1, x);
      z = uminu(t2, y);  t2 = umaxu(t2, y);
      t3 = umaxu(t3, z);
    }
  }
}

__global__ __launch_bounds__(256) void select_kernel(
    const unsigned short* __restrict__ S,    // [chunk][4096] fp16
    int2* __restrict__ cand2, int c0, int level) {
  int wave = threadIdx.x >> 6, lane = threadIdx.x & 63;
  int rlocal = blockIdx.x * 4 + wave;
  const uint4* row = (const uint4*)(S + (size_t)rlocal * 4096);  // 512 uint4/row

  uint4 v[8];
#pragma unroll
  for (int i = 0; i < 8; ++i) v[i] = row[i * 64 + lane];   // 1KB/wave/iter, coalesced

  const unsigned lane8 = (unsigned)lane * 8u;
  unsigned t0, t1, t2, t3;
  top4_build<false>(v, lane8, 0u, t0, t1, t2, t3);

  unsigned myres = 0u;
#pragma clang loop unroll(disable)
  for (int r = 0; r < NCAND; ++r) {
    unsigned g = t0;
#pragma unroll
    for (int m = 1; m < 64; m <<= 1) {
      unsigned o = (unsigned)__shfl_xor((int)g, m);
      g = umaxu(g, o);
    }
    if (t0 == g) {               // unique winner (pos embedded in key)
      t0 = t1; t1 = t2; t2 = t3; t3 = 0u;
      if (t0 == 0u)              // list exhausted: exact rebuild of remaining
        top4_build<true>(v, lane8, g, t0, t1, t2, t3);
    }
    if (lane == r) myres = g;
  }

  size_t base = ((size_t)(c0 + rlocal) * 3 + level) * NCAND;
  if (lane < NCAND) {
    unsigned k16 = myres >> 16;
    unsigned ob = k16 ^ ((k16 & 0x8000u) ? 0x8000u : 0xFFFFu);  // undo key transform
    cand2[base + lane] = make_int2((int)(myres & 0xFFFFu),
                                   __float_as_int(h2f((unsigned short)ob)));
  }
}

// ---------- classify: ARRAY-FREE, lane-per-candidate ----------
// Round 3/4 lesson (VGPR 28-44, VALUBusy 1.8-24%, 185-216us): any per-lane NCAND array
// (av[]/idx[]/ew[]) spills to scratch in these small kernels. Here lane j owns candidate
// j only; comparisons via shfl-consumed scalars, masks via ballot, softmax via 16-lane
// butterflies, writes via rank=popc(selm below me). ~16 VGPR, no arrays.
__global__ __launch_bounds__(256) void classify_kernel(
    const int2* __restrict__ cand2, const float* __restrict__ route_w,
    int2* __restrict__ worklist, int* __restrict__ counter, int slot,
    int* __restrict__ sel_idx, float* __restrict__ sel_w,
    int c0, int level) {
  const int wave = threadIdx.x >> 6, lane = threadIdx.x & 63;
  const int row = c0 + blockIdx.x * 4 + wave;
  const int me = lane & 15;
  const size_t cb = ((size_t)row * 3 + level) * NCAND;

  // lanes 16-63 hold replicas of lanes 0-15 (same me) -> all reductions wave-uniform
  int2 pr = cand2[cb + me];
  float my_av = __int_as_float(pr.y);
  int   my_idx = pr.x;

  int cnt_hi = 0, cnt_lo = 0;
#pragma unroll
  for (int j = 0; j < NCAND; ++j) {
    float aj = __shfl(my_av, j);             // consumed immediately, never stored
    cnt_hi += (aj > my_av + DELTA) ? 1 : 0;
    cnt_lo += (j != me && aj > my_av - DELTA) ? 1 : 0;
  }
  const bool is_out = (cnt_hi >= TOPK);
  const bool is_cin = !is_out && (cnt_lo <= TOPK - 1);
  const bool is_amb = !is_out && !is_cin;
  const int cin_mask = (int)(__ballot(lane < 16 && is_cin) & 0xFFFFu);
  const int amb_mask = (int)(__ballot(lane < 16 && is_amb) & 0xFFFFu);

  const int need = TOPK - __popc((unsigned)cin_mask);
  const bool hard = (need > 0) && (__popc((unsigned)amb_mask) > need);

  if (hard) {
    if (lane == 0) {
      int e = atomicAdd(counter + slot, 1);
      worklist[e] = make_int2(row, cin_mask | (amb_mask << 16));
    }
    return;
  }

  // easy: selection fully determined; popc(selm)==TOPK (see margin-classification proof)
  const int selm = (need > 0) ? (cin_mask | amb_mask) : cin_mask;
  const bool sel = ((selm >> me) & 1) != 0;

  float mx = sel ? my_av : -INFINITY;
#pragma unroll
  for (int m = 1; m < 16; m <<= 1) mx = fmaxf(mx, __shfl_xor(mx, m));
  float ew = sel ? expf(my_av - mx) : 0.f;
  float sum = ew;
#pragma unroll
  for (int m = 1; m < 16; m <<= 1) sum += __shfl_xor(sum, m);

  if (sel && lane < 16) {
    float rw = route_w[(size_t)row * 3 + level] / sum;
    int rank = __popc((unsigned)selm & ((1u << me) - 1u));
    size_t b8 = ((size_t)row * 3 + level) * TOPK;
    sel_idx[b8 + rank] = my_idx;
    sel_w[b8 + rank]  = ew * rw;
  }
}

// ---------- rescore: one wave per hard row from the worklist; fp64 exact dots ----------
__global__ __launch_bounds__(256) void rescore_kernel(
    const float* __restrict__ q, const float* __restrict__ Kl,
    const float* __restrict__ sal, const float* __restrict__ route_w,
    const int2* __restrict__ cand2,
    const int2* __restrict__ worklist, const int* __restrict__ counter, int slot,
    int level, int* __restrict__ sel_idx, float* __restrict__ sel_w) {
  const int wid  = blockIdx.x * 4 + (threadIdx.x >> 6);
  const int lane = threadIdx.x & 63;
  const int n = counter[slot];
  if (wid >= n) return;

  const int2 e = worklist[wid];
  const int row = e.x;
  const int cin_mask = e.y & 0xFFFF;
  const int amb_mask = (e.y >> 16) & 0xFFFF;
  const int need = TOPK - __popc((unsigned)cin_mask);

  float av[NCAND]; int idx[NCAND];
  {
    size_t cb = ((size_t)row * 3 + level) * NCAND;
#pragma unroll
    for (int c = 0; c < NCAND; ++c) {
      int2 pr = cand2[cb + c];
      idx[c] = pr.x; av[c] = __int_as_float(pr.y);
    }
  }

  // q row into regs (16 floats/lane, coalesced)
  float qr[16];
  {
    const float4* qp = (const float4*)(q + (size_t)row * 1024) + lane * 4;
#pragma unroll
    for (int m4 = 0; m4 < 4; ++m4) {
      float4 tv = qp[m4];
      qr[m4 * 4 + 0] = tv.x; qr[m4 * 4 + 1] = tv.y;
      qr[m4 * 4 + 2] = tv.z; qr[m4 * 4 + 3] = tv.w;
    }
  }

  double ex[NCAND];
#pragma unroll
  for (int c = 0; c < NCAND; ++c) {
    if (!((amb_mask >> c) & 1)) continue;
    int sx = idx[c];
    const float4* kr = (const float4*)(Kl + (size_t)sx * 1024) + lane * 4;
    double acc = 0.0;
#pragma unroll
    for (int m4 = 0; m4 < 4; ++m4) {
      float4 kv = kr[m4];
      acc = fma((double)qr[m4 * 4 + 0], (double)kv.x, acc);
      acc = fma((double)qr[m4 * 4 + 1], (double)kv.y, acc);
      acc = fma((double)qr[m4 * 4 + 2], (double)kv.z, acc);
      acc = fma((double)qr[m4 * 4 + 3], (double)kv.w, acc);
    }
#pragma unroll
    for (int m = 1; m < 64; m <<= 1) acc += __shfl_xor(acc, m);
    ex[c] = acc * 0.03125 + (double)sal[sx];
  }

  // selected mask: certain-in plus the 'need' best ambiguous by exact score
  int selm = cin_mask;
  unsigned rem = (unsigned)amb_mask;
  for (int p = 0; p < need; ++p) {
    double bs = -1e300; int bc = 0;
#pragma unroll
    for (int c = 0; c < NCAND; ++c)
      if ((rem >> c) & 1)
        if (ex[c] > bs) { bs = ex[c]; bc = c; }
    rem &= ~(1u << bc);
    selm |= (1 << bc);
  }

  // weights: softmax over approx scores of the selected 8, fold route weight
  float mx = -INFINITY;
#pragma unroll
  for (int j = 0; j < NCAND; ++j)
    if ((selm >> j) & 1) mx = fmaxf(mx, av[j]);
  float ew[NCAND]; float sum = 0.f;
#pragma unroll
  for (int j = 0; j < NCAND; ++j) {
    ew[j] = 0.f;
    if ((selm >> j) & 1) { ew[j] = expf(av[j] - mx); sum += ew[j]; }
  }
  if (lane == 0) {
    float rw = route_w[(size_t)row * 3 + level] / sum;
    size_t b8 = ((size_t)row * 3 + level) * TOPK;
    int k = 0;
#pragma unroll
    for (int j = 0; j < NCAND; ++j)
      if ((selm >> j) & 1) {
        sel_idx[b8 + k] = idx[j];
        sel_w[b8 + k]  = ew[j] * rw;
        ++k;
      }
  }
}

// ---------- final: out[row,:] = sum over 24 (level,k) of w * V16[level,idx,:] ----------
__global__ __launch_bounds__(128) void final_kernel(
    const _Float16* __restrict__ V16, const int* __restrict__ sel_idx,
    const float* __restrict__ sel_w, float* __restrict__ out) {
  __shared__ float wv[24];
  __shared__ int   widx[24];
  int row = blockIdx.x, t = threadIdx.x;   // t in [0,128): 8 halves each
  if (t < 24) {
    int l = t >> 3, j = t & 7;
    size_t base = ((size_t)row * 3 + l) * TOPK + j;
    wv[t]   = sel_w[base];
    widx[t] = l * SLOTS + sel_idx[base];
  }
  __syncthreads();
  float acc[8] = {0.f, 0.f, 0.f, 0.f, 0.f, 0.f, 0.f, 0.f};
  for (int i = 0; i < 24; ++i) {
    float w = wv[i];
    f16x8 v = *(const f16x8*)(V16 + (size_t)widx[i] * 1024 + t * 8);
#pragma unroll
    for (int e = 0; e < 8; ++e) acc[e] += w * (float)v[e];
  }
  float4* op = (float4*)(out + (size_t)row * 1024) + t * 2;
  op[0] = make_float4(acc[0], acc[1], acc[2], acc[3]);
  op[1] = make_float4(acc[4], acc[5], acc[6], acc[7]);
}

// ---------- launch ----------
extern "C" void kernel_launch(void* const* d_in, const int* in_sizes, int n_in,
                              void* d_out, int out_size, void* d_ws, size_t ws_size,
                              hipStream_t stream) {
  const float* q   = (const float*)d_in[0];
  const float* Ks  = (const float*)d_in[1];
  const float* Vs  = (const float*)d_in[2];
  const float* sal = (const float*)d_in[3];
  const float* W1  = (const float*)d_in[4];
  const float* b1  = (const float*)d_in[5];
  const float* W2  = (const float*)d_in[6];
  const float* b2  = (const float*)d_in[7];
  float* out = (float*)d_out;
  (void)in_sizes; (void)n_in; (void)out_size;

  char* p = (char*)d_ws;
  auto alloc = [&](size_t bytes) -> char* {
    char* r = p; p += (bytes + 255) & ~(size_t)255; return r;
  };
  // fixed (live across the whole pipeline)
  char*      q8    = alloc((size_t)BT * 1024);
  char*      K8    = alloc((size_t)LEVELS * SLOTS * 1024);
  _Float16*  V16   = (_Float16*)alloc((size_t)LEVELS * SLOTS * 1024 * 2);
  float*     route = (float*)alloc((size_t)BT * 3 * 4);
  int2*      cand2 = (int2*)alloc((size_t)BT * 3 * NCAND * 8);
  int*       s_idx = (int*)alloc((size_t)BT * 3 * TOPK * 4);
  float*     s_w   = (float*)alloc((size_t)BT * 3 * TOPK * 4);
  int*       ctrs  = (int*)alloc(32 * 4);
  int2*      wlist = (int2*)alloc((size_t)BT * 8);
  size_t fixed = (size_t)(p - (char*)d_ws);

  // aliased region: router temps (dead before scores loop) overlap scores buffer
  char* ali = p;
  unsigned short* qh   = (unsigned short*)alloc((size_t)BT * 1024 * 2);
  unsigned short* W1Th = (unsigned short*)alloc((size_t)HDIM * 1024 * 2);
  unsigned short* W1Tl = (unsigned short*)alloc((size_t)HDIM * 1024 * 2);
  float*          h    = (float*)alloc((size_t)BT * HDIM * 4);
  size_t router_bytes = (size_t)(p - ali);

  unsigned short* scores = (unsigned short*)ali;   // fp16 [chunk][4096]
  int chunk = 2048;
  const int opts[4] = {16384, 8192, 4096, 2048};
  for (int i = 0; i < 4; ++i) {
    size_t scores_b = (size_t)opts[i] * SLOTS * 2;
    size_t need = fixed + (scores_b > router_bytes ? scores_b : router_bytes);
    if (need <= ws_size) { chunk = opts[i]; break; }
  }

  // 0) counters
  init_counters_kernel<<<1, 32, 0, stream>>>(ctrs);

  // 1) conversions
  conv_q8h_kernel<<<(BT * 1024 / 16) / 256, 256, 0, stream>>>(q, q8, qh);
  conv_i8_kernel<<<(LEVELS * SLOTS * 1024 / 16) / 256, 256, 0, stream>>>(Ks, K8, KSCALE);
  conv_v16_kernel<<<(LEVELS * SLOTS * 1024 / 8) / 256, 256, 0, stream>>>(Vs, V16);
  conv_w1t_kernel<<<(1024 * HDIM) / 256, 256, 0, stream>>>(W1, W1Th, W1Tl);

  // 2) router
  gemm_router_kernel<<<dim3(HDIM / 128, BT / 128), 256, 0, stream>>>(qh, W1Th, W1Tl, b1, h);
  router_head_kernel<<<BT / 4, 256, 0, stream>>>(h, W2, b2, route);

  // 3) per level, per chunk: i8 scores -> top-16 -> classify (easy done) -> worklist rescore
  int slot = 0;
  for (int level = 0; level < LEVELS; ++level) {
    const char*  K8L  = K8 + (size_t)level * SLOTS * 1024;
    const float* salL = sal + (size_t)level * SLOTS;
    const float* KsL  = Ks + (size_t)level * SLOTS * 1024;
    for (int c0 = 0; c0 < BT; c0 += chunk, ++slot) {
      gemm_scores_i8_kernel<<<dim3(SLOTS / 128, chunk / 128), 256, 0, stream>>>(
          q8 + (size_t)c0 * 1024, K8L, salL, scores);
      select_kernel<<<chunk / 4, 256, 0, stream>>>(scores, cand2, c0, level);
      classify_kernel<<<chunk / 4, 256, 0, stream>>>(cand2, route, wlist, ctrs, slot,
                                                     s_idx, s_w, c0, level);
      rescore_kernel<<<chunk / 4, 256, 0, stream>>>(q, KsL, salL, route, cand2, wlist, ctrs, slot,
                                                    level, s_idx, s_w);
    }
  }

  // 4) gather + weighted sum
  final_kernel<<<BT, 128, 0, stream>>>(V16, s_idx, s_w, out);
}

// Round 6
// 977.795 us; speedup vs baseline: 1.5381x; 1.5342x over previous
//
#include <hip/hip_runtime.h>
#include <hip/hip_bf16.h>
#include <math.h>

#define D_MODEL 1024
#define SLOTS   4096
#define LEVELS  3
#define BT      16384   // B*T = 4*4096
#define HDIM    512
#define NCAND   16
#define TOPK    8

// i8 quantization scales:
// q ~ N(0,1): clip +-5.08 sigma (scale 25); K ~ U(+-0.03424): scale 3700 never clips.
// per-score approx error sigma ~= 2.4e-4 (i8) + 7.8e-5 (K i8) + 3e-5 (fp16 store).
#define QSCALE 25.0f
#define KSCALE 3700.0f
// membership ambiguity margin: >=7 sigma of pairwise approx error
#define DELTA  2.5e-3f

typedef float    f32x4  __attribute__((ext_vector_type(4)));
typedef int      i32x4  __attribute__((ext_vector_type(4)));
typedef __bf16   bf16x8 __attribute__((ext_vector_type(8)));
typedef _Float16 f16x8  __attribute__((ext_vector_type(8)));

// async global->LDS, 16B per lane. LDS dest is wave-uniform base + lane*16.
__device__ __forceinline__ void gl_lds16(const void* g, void* l) {
  __builtin_amdgcn_global_load_lds((const __attribute__((address_space(1))) void*)g,
                                   (__attribute__((address_space(3))) void*)l, 16, 0, 0);
}

// ---------- fp helpers ----------
__device__ __forceinline__ unsigned short f2bf(float f) {
  union { float f; unsigned u; } v; v.f = f;
  unsigned r = (v.u + 0x7fffu + ((v.u >> 16) & 1u)) >> 16;
  return (unsigned short)r;
}
__device__ __forceinline__ float bf2f(unsigned short b) {
  union { unsigned u; float f; } v; v.u = ((unsigned)b) << 16; return v.f;
}
__device__ __forceinline__ unsigned short f2h_bits(float f) {
  union { _Float16 h; unsigned short u; } v; v.h = (_Float16)f; return v.u;
}
__device__ __forceinline__ float h2f(unsigned short b) {
  union { unsigned short u; _Float16 h; } v; v.u = b; return (float)v.h;
}
__device__ __forceinline__ int q_i8(float f, float scale) {
  float v = f * scale;
  v = fminf(fmaxf(v, -127.0f), 127.0f);
  return (int)rintf(v);
}
__device__ __forceinline__ unsigned umaxu(unsigned a, unsigned b) { return a > b ? a : b; }
__device__ __forceinline__ unsigned uminu(unsigned a, unsigned b) { return a < b ? a : b; }

// ---------- conversion kernels ----------
__global__ __launch_bounds__(256) void conv_i8_kernel(const float* __restrict__ src,
                                                      char* __restrict__ dst, float scale) {
  int i = blockIdx.x * 256 + threadIdx.x;          // 16-elem index
  const float4* s = (const float4*)src + i * 4;
  int w[4];
#pragma unroll
  for (int g = 0; g < 4; ++g) {
    float4 v = s[g];
    int b0 = q_i8(v.x, scale) & 255, b1 = q_i8(v.y, scale) & 255;
    int b2 = q_i8(v.z, scale) & 255, b3 = q_i8(v.w, scale) & 255;
    w[g] = b0 | (b1 << 8) | (b2 << 16) | (b3 << 24);
  }
  ((int4*)dst)[i] = make_int4(w[0], w[1], w[2], w[3]);
}

// fused: q -> i8 (for scores GEMM) AND bf16-hi (for router A operand)
__global__ __launch_bounds__(256) void conv_q8h_kernel(const float* __restrict__ q,
                                                       char* __restrict__ q8,
                                                       unsigned short* __restrict__ qh) {
  int i = blockIdx.x * 256 + threadIdx.x;          // 16-elem index
  const float4* s = (const float4*)q + i * 4;
  int w[4]; unsigned hh[8];
#pragma unroll
  for (int g = 0; g < 4; ++g) {
    float4 v = s[g];
    int b0 = q_i8(v.x, QSCALE) & 255, b1 = q_i8(v.y, QSCALE) & 255;
    int b2 = q_i8(v.z, QSCALE) & 255, b3 = q_i8(v.w, QSCALE) & 255;
    w[g] = b0 | (b1 << 8) | (b2 << 16) | (b3 << 24);
    hh[g * 2 + 0] = (unsigned)f2bf(v.x) | ((unsigned)f2bf(v.y) << 16);
    hh[g * 2 + 1] = (unsigned)f2bf(v.z) | ((unsigned)f2bf(v.w) << 16);
  }
  ((int4*)q8)[i] = make_int4(w[0], w[1], w[2], w[3]);
  uint4* qp = (uint4*)qh + i * 2;
  qp[0] = make_uint4(hh[0], hh[1], hh[2], hh[3]);
  qp[1] = make_uint4(hh[4], hh[5], hh[6], hh[7]);
}

__global__ __launch_bounds__(256) void conv_w1t_kernel(const float* __restrict__ W1,
                                                       unsigned short* __restrict__ Wh,
                                                       unsigned short* __restrict__ Wl) {
  int e = blockIdx.x * 256 + threadIdx.x;          // e = k*512 + n
  int k = e >> 9, n = e & 511;
  float f = W1[e];
  unsigned short hb = f2bf(f);
  Wh[(size_t)n * 1024 + k] = hb;
  Wl[(size_t)n * 1024 + k] = f2bf(f - bf2f(hb));
}

// V -> fp16 for the final gather (halves gather bytes; err <= 1.5e-5, negligible)
__global__ __launch_bounds__(256) void conv_v16_kernel(const float* __restrict__ Vs,
                                                       _Float16* __restrict__ V16) {
  int i = blockIdx.x * 256 + threadIdx.x;          // 8-elem index
  const float4* s = (const float4*)Vs + i * 2;
  float4 a = s[0], b = s[1];
  f16x8 o;
  o[0] = (_Float16)a.x; o[1] = (_Float16)a.y; o[2] = (_Float16)a.z; o[3] = (_Float16)a.w;
  o[4] = (_Float16)b.x; o[5] = (_Float16)b.y; o[6] = (_Float16)b.z; o[7] = (_Float16)b.w;
  ((f16x8*)V16)[i] = o;
}

// ---------- scores GEMM (i8): C[m,s] = fp16((q8.K8)*dq + sal[s]) ----------
__global__ __launch_bounds__(256) void gemm_scores_i8_kernel(
    const char* __restrict__ A,   // [rows][1024] i8 (chunk base pre-applied)
    const char* __restrict__ B,   // [4096][1024] i8 (level's K)
    const float* __restrict__ sal,
    unsigned short* __restrict__ C) {   // [chunk][4096] fp16
  __shared__ __align__(16) char As[128 * 64];
  __shared__ __align__(16) char Bs[128 * 64];
  const int tid = threadIdx.x;
  const int bx = blockIdx.x, by = blockIdx.y;
  const int lane = tid & 63, wave = tid >> 6;
  const int wm = wave >> 1, wn = wave & 1;

  const char* gA = A + (size_t)(by * 128 + (tid >> 2)) * 1024 + (tid & 3) * 16;
  const char* gB = B + (size_t)(bx * 128 + (tid >> 2)) * 1024 + (tid & 3) * 16;
  char* lA = As + tid * 16;
  char* lB = Bs + tid * 16;

  i32x4 acc[4][4] = {};

  for (int k0 = 0; k0 < 1024; k0 += 64) {
    __syncthreads();
    gl_lds16(gA + k0,             lA);
    gl_lds16(gA + 64 * 1024 + k0, lA + 64 * 64);
    gl_lds16(gB + k0,             lB);
    gl_lds16(gB + 64 * 1024 + k0, lB + 64 * 64);
    __syncthreads();

    const int fr = lane & 15, fk = (lane >> 4) * 16;
    i32x4 a[4], b[4];
#pragma unroll
    for (int i = 0; i < 4; ++i) a[i] = *(const i32x4*)(As + (wm * 64 + i * 16 + fr) * 64 + fk);
#pragma unroll
    for (int j = 0; j < 4; ++j) b[j] = *(const i32x4*)(Bs + (wn * 64 + j * 16 + fr) * 64 + fk);
#pragma unroll
    for (int i = 0; i < 4; ++i)
#pragma unroll
      for (int j = 0; j < 4; ++j)
        acc[i][j] = __builtin_amdgcn_mfma_i32_16x16x64_i8(a[i], b[j], acc[i][j], 0, 0, 0);
  }

  const float dq = 1.0f / (QSCALE * KSCALE * 32.0f);
  const int rr = (lane >> 4) * 4, cc = lane & 15;
#pragma unroll
  for (int i = 0; i < 4; ++i)
#pragma unroll
    for (int j = 0; j < 4; ++j) {
      int col = bx * 128 + wn * 64 + j * 16 + cc;
      float s = sal[col];
      int rowb = by * 128 + wm * 64 + i * 16 + rr;
#pragma unroll
      for (int r = 0; r < 4; ++r)
        C[(size_t)(rowb + r) * 4096 + col] = f2h_bits((float)acc[i][j][r] * dq + s);
    }
}

// ---------- router GEMM: h = relu(q @ W1 + b1) ----------
__global__ __launch_bounds__(256) void gemm_router_kernel(
    const unsigned short* __restrict__ Ah,
    const unsigned short* __restrict__ Bh, const unsigned short* __restrict__ Bl,
    const float* __restrict__ b1, float* __restrict__ H) {
  __shared__ __align__(16) unsigned short Ash[128 * 32];
  __shared__ __align__(16) unsigned short Bsh[128 * 32], Bsl[128 * 32];
  const int tid = threadIdx.x;
  const int bx = blockIdx.x, by = blockIdx.y;
  const int lane = tid & 63, wave = tid >> 6;
  const int wm = wave >> 1, wn = wave & 1;

  const int s_row = wave * 16 + (lane >> 2);
  const int s_c8  = (lane & 3) * 8;
  const unsigned short* gAh = Ah + (size_t)(by * 128 + s_row) * 1024 + s_c8;
  const unsigned short* gBh = Bh + (size_t)(bx * 128 + s_row) * 1024 + s_c8;
  const unsigned short* gBl = Bl + (size_t)(bx * 128 + s_row) * 1024 + s_c8;
  unsigned short* lAh = Ash + s_row * 32 + s_c8;
  unsigned short* lBh = Bsh + s_row * 32 + s_c8;
  unsigned short* lBl = Bsl + s_row * 32 + s_c8;

  f32x4 acc[4][4] = {};

  for (int k0 = 0; k0 < 1024; k0 += 32) {
    __syncthreads();
    gl_lds16(gAh + k0,             lAh);
    gl_lds16(gAh + 64 * 1024 + k0, lAh + 64 * 32);
    gl_lds16(gBh + k0,             lBh);
    gl_lds16(gBh + 64 * 1024 + k0, lBh + 64 * 32);
    gl_lds16(gBl + k0,             lBl);
    gl_lds16(gBl + 64 * 1024 + k0, lBl + 64 * 32);
    __syncthreads();

    const int fr = lane & 15, fk = (lane >> 4) * 8;
    bf16x8 ah[4], bh[4], bl[4];
#pragma unroll
    for (int i = 0; i < 4; ++i) {
      int off = (wm * 64 + i * 16 + fr) * 32 + fk;
      ah[i] = *(const bf16x8*)(Ash + off);
    }
#pragma unroll
    for (int j = 0; j < 4; ++j) {
      int off = (wn * 64 + j * 16 + fr) * 32 + fk;
      bh[j] = *(const bf16x8*)(Bsh + off);
      bl[j] = *(const bf16x8*)(Bsl + off);
    }
#pragma unroll
    for (int i = 0; i < 4; ++i)
#pragma unroll
      for (int j = 0; j < 4; ++j) {
        acc[i][j] = __builtin_amdgcn_mfma_f32_16x16x32_bf16(ah[i], bh[j], acc[i][j], 0, 0, 0);
        acc[i][j] = __builtin_amdgcn_mfma_f32_16x16x32_bf16(ah[i], bl[j], acc[i][j], 0, 0, 0);
      }
  }

  const int rr = (lane >> 4) * 4, cc = lane & 15;
#pragma unroll
  for (int i = 0; i < 4; ++i)
#pragma unroll
    for (int j = 0; j < 4; ++j) {
      int col = bx * 128 + wn * 64 + j * 16 + cc;
      float bias = b1[col];
      int rowb = by * 128 + wm * 64 + i * 16 + rr;
#pragma unroll
      for (int r = 0; r < 4; ++r) {
        float v = acc[i][j][r] + bias;
        H[(size_t)(rowb + r) * HDIM + col] = v > 0.0f ? v : 0.0f;
      }
    }
}

// ---------- router head ----------
__global__ __launch_bounds__(256) void router_head_kernel(
    const float* __restrict__ H, const float* __restrict__ W2,
    const float* __restrict__ b2, float* __restrict__ route_w) {
  int wave = threadIdx.x >> 6, lane = threadIdx.x & 63;
  int row = blockIdx.x * 4 + wave;
  float a0 = 0.f, a1 = 0.f, a2 = 0.f;
#pragma unroll
  for (int k = 0; k < 8; ++k) {
    int d = k * 64 + lane;
    float hv = H[(size_t)row * HDIM + d];
    a0 += hv * W2[d * 3 + 0];
    a1 += hv * W2[d * 3 + 1];
    a2 += hv * W2[d * 3 + 2];
  }
#pragma unroll
  for (int m = 1; m < 64; m <<= 1) {
    a0 += __shfl_xor(a0, m); a1 += __shfl_xor(a1, m); a2 += __shfl_xor(a2, m);
  }
  if (lane == 0) {
    float l0 = a0 + b2[0], l1 = a1 + b2[1], l2 = a2 + b2[2];
    float mx = fmaxf(l0, fmaxf(l1, l2));
    float e0 = expf(l0 - mx), e1 = expf(l1 - mx), e2 = expf(l2 - mx);
    float inv = 1.0f / (e0 + e1 + e2);
    route_w[(size_t)row * 3 + 0] = e0 * inv;
    route_w[(size_t)row * 3 + 1] = e1 * inv;
    route_w[(size_t)row * 3 + 2] = e2 * inv;
  }
}

// ---------- select: ONE WAVE per row, top-16 of 4096 fp16 scores (register-only) ----------
template<bool FILTER>
__device__ __forceinline__ void top4_build(const uint4 (&v)[8], unsigned lane8, unsigned bound,
                                           unsigned &t0, unsigned &t1, unsigned &t2, unsigned &t3) {
  t0 = t1 = t2 = t3 = 0u;
#pragma unroll
  for (int i = 0; i < 8; ++i) {
    unsigned wds[4] = {v[i].x, v[i].y, v[i].z, v[i].w};
#pragma unroll
    for (int g = 0; g < 4; ++g) {
      unsigned w = wds[g];
      unsigned s = w & 0x80008000u;
      // per-half: key16 = v ^ (sign ? 0xFFFF : 0x8000); packed in one u32 (IEEE sign-mag)
      unsigned key2 = (w ^ 0x80008000u) ^ (s - (s >> 15));
      unsigned pb = lane8 + (unsigned)(i * 512 + g * 2);
      unsigned kA = (key2 << 16) | pb;                 // low half element
      unsigned kB = (key2 & 0xFFFF0000u) | (pb + 1u);  // high half element
      if (FILTER) {
        if (kA >= bound) kA = 0u;
        if (kB >= bound) kB = 0u;
      }
      unsigned x, y, z;
      x = uminu(t0, kA); t0 = umaxu(t0, kA);
      y = uminu(t1, x);  t1 = umaxu(t1, x);
      z = uminu(t2, y);  t2 = umaxu(t2, y);
      t3 = umaxu(t3, z);
      x = uminu(t0, kB); t0 = umaxu(t0, kB);
      y = uminu(t1, x);  t1 = umaxu(t1, x);
      z = uminu(t2, y);  t2 = umaxu(t2, y);
      t3 = umaxu(t3, z);
    }
  }
}

__global__ __launch_bounds__(256) void select_kernel(
    const unsigned short* __restrict__ S,    // [chunk][4096] fp16
    int2* __restrict__ cand2, int c0, int level) {
  int wave = threadIdx.x >> 6, lane = threadIdx.x & 63;
  int rlocal = blockIdx.x * 4 + wave;
  const uint4* row = (const uint4*)(S + (size_t)rlocal * 4096);  // 512 uint4/row

  uint4 v[8];
#pragma unroll
  for (int i = 0; i < 8; ++i) v[i] = row[i * 64 + lane];   // 1KB/wave/iter, coalesced

  const unsigned lane8 = (unsigned)lane * 8u;
  unsigned t0, t1, t2, t3;
  top4_build<false>(v, lane8, 0u, t0, t1, t2, t3);

  unsigned myres = 0u;
#pragma clang loop unroll(disable)
  for (int r = 0; r < NCAND; ++r) {
    unsigned g = t0;
#pragma unroll
    for (int m = 1; m < 64; m <<= 1) {
      unsigned o = (unsigned)__shfl_xor((int)g, m);
      g = umaxu(g, o);
    }
    if (t0 == g) {               // unique winner (pos embedded in key)
      t0 = t1; t1 = t2; t2 = t3; t3 = 0u;
      if (t0 == 0u)              // list exhausted: exact rebuild of remaining
        top4_build<true>(v, lane8, g, t0, t1, t2, t3);
    }
    if (lane == r) myres = g;
  }

  size_t base = ((size_t)(c0 + rlocal) * 3 + level) * NCAND;
  if (lane < NCAND) {
    unsigned k16 = myres >> 16;
    unsigned ob = k16 ^ ((k16 & 0x8000u) ? 0x8000u : 0xFFFFu);  // undo key transform
    cand2[base + lane] = make_int2((int)(myres & 0xFFFFu),
                                   __float_as_int(h2f((unsigned short)ob)));
  }
}

// ---------- classify: array-free, lane-per-candidate, NO ATOMICS ----------
// Post-mortem history: r3 (216us) and r4 (185us) were blamed on scratch spill; r5's
// array-free version (VGPR 16, no spill) still took 181us at VALUBusy 1.6% -> the real
// cost was the RETURNING same-address atomicAdd (worklist compaction): ~5K waves/dispatch
// serialized at the coherence point. Fix: per-row hardmask store (no atomic); rescore
// early-exits on easy rows (its grid was full-size anyway).
__global__ __launch_bounds__(256) void classify_kernel(
    const int2* __restrict__ cand2, const float* __restrict__ route_w,
    int* __restrict__ hardmask,
    int* __restrict__ sel_idx, float* __restrict__ sel_w,
    int c0, int level) {
  const int wave = threadIdx.x >> 6, lane = threadIdx.x & 63;
  const int row = c0 + blockIdx.x * 4 + wave;
  const int me = lane & 15;
  const size_t cb = ((size_t)row * 3 + level) * NCAND;

  // lanes 16-63 hold replicas of lanes 0-15 (same me) -> all reductions wave-uniform
  int2 pr = cand2[cb + me];
  float my_av = __int_as_float(pr.y);
  int   my_idx = pr.x;

  int cnt_hi = 0, cnt_lo = 0;
#pragma unroll
  for (int j = 0; j < NCAND; ++j) {
    float aj = __shfl(my_av, j);             // consumed immediately, never stored
    cnt_hi += (aj > my_av + DELTA) ? 1 : 0;
    cnt_lo += (j != me && aj > my_av - DELTA) ? 1 : 0;
  }
  const bool is_out = (cnt_hi >= TOPK);
  const bool is_cin = !is_out && (cnt_lo <= TOPK - 1);
  const bool is_amb = !is_out && !is_cin;
  const int cin_mask = (int)(__ballot(lane < 16 && is_cin) & 0xFFFFu);
  const int amb_mask = (int)(__ballot(lane < 16 && is_amb) & 0xFFFFu);

  const int need = TOPK - __popc((unsigned)cin_mask);
  const bool hard = (need > 0) && (__popc((unsigned)amb_mask) > need);

  if (lane == 0)
    hardmask[(size_t)row * 3 + level] = hard ? (cin_mask | (amb_mask << 16)) : 0;
  if (hard) return;

  // easy: selection fully determined; popc(selm)==TOPK
  const int selm = (need > 0) ? (cin_mask | amb_mask) : cin_mask;
  const bool sel = ((selm >> me) & 1) != 0;

  float mx = sel ? my_av : -INFINITY;
#pragma unroll
  for (int m = 1; m < 16; m <<= 1) mx = fmaxf(mx, __shfl_xor(mx, m));
  float ew = sel ? expf(my_av - mx) : 0.f;
  float sum = ew;
#pragma unroll
  for (int m = 1; m < 16; m <<= 1) sum += __shfl_xor(sum, m);

  if (sel && lane < 16) {
    float rw = route_w[(size_t)row * 3 + level] / sum;
    int rank = __popc((unsigned)selm & ((1u << me) - 1u));
    size_t b8 = ((size_t)row * 3 + level) * TOPK;
    sel_idx[b8 + rank] = my_idx;
    sel_w[b8 + rank]  = ew * rw;
  }
}

// ---------- rescore: one wave per row; early-exit unless hardmask says hard ----------
__global__ __launch_bounds__(256) void rescore_kernel(
    const float* __restrict__ q, const float* __restrict__ Kl,
    const float* __restrict__ sal, const float* __restrict__ route_w,
    const int2* __restrict__ cand2, const int* __restrict__ hardmask,
    int level, int c0, int* __restrict__ sel_idx, float* __restrict__ sel_w) {
  const int row  = c0 + blockIdx.x * 4 + (threadIdx.x >> 6);
  const int lane = threadIdx.x & 63;
  const int hm = hardmask[(size_t)row * 3 + level];
  if (hm == 0) return;

  const int cin_mask = hm & 0xFFFF;
  const int amb_mask = (hm >> 16) & 0xFFFF;
  const int need = TOPK - __popc((unsigned)cin_mask);

  float av[NCAND]; int idx[NCAND];
  {
    size_t cb = ((size_t)row * 3 + level) * NCAND;
#pragma unroll
    for (int c = 0; c < NCAND; ++c) {
      int2 pr = cand2[cb + c];
      idx[c] = pr.x; av[c] = __int_as_float(pr.y);
    }
  }

  // q row into regs (16 floats/lane, coalesced)
  float qr[16];
  {
    const float4* qp = (const float4*)(q + (size_t)row * 1024) + lane * 4;
#pragma unroll
    for (int m4 = 0; m4 < 4; ++m4) {
      float4 tv = qp[m4];
      qr[m4 * 4 + 0] = tv.x; qr[m4 * 4 + 1] = tv.y;
      qr[m4 * 4 + 2] = tv.z; qr[m4 * 4 + 3] = tv.w;
    }
  }

  double ex[NCAND];
#pragma unroll
  for (int c = 0; c < NCAND; ++c) {
    if (!((amb_mask >> c) & 1)) continue;
    int sx = idx[c];
    const float4* kr = (const float4*)(Kl + (size_t)sx * 1024) + lane * 4;
    double acc = 0.0;
#pragma unroll
    for (int m4 = 0; m4 < 4; ++m4) {
      float4 kv = kr[m4];
      acc = fma((double)qr[m4 * 4 + 0], (double)kv.x, acc);
      acc = fma((double)qr[m4 * 4 + 1], (double)kv.y, acc);
      acc = fma((double)qr[m4 * 4 + 2], (double)kv.z, acc);
      acc = fma((double)qr[m4 * 4 + 3], (double)kv.w, acc);
    }
#pragma unroll
    for (int m = 1; m < 64; m <<= 1) acc += __shfl_xor(acc, m);
    ex[c] = acc * 0.03125 + (double)sal[sx];
  }

  // selected mask: certain-in plus the 'need' best ambiguous by exact score
  int selm = cin_mask;
  unsigned rem = (unsigned)amb_mask;
  for (int p = 0; p < need; ++p) {
    double bs = -1e300; int bc = 0;
#pragma unroll
    for (int c = 0; c < NCAND; ++c)
      if ((rem >> c) & 1)
        if (ex[c] > bs) { bs = ex[c]; bc = c; }
    rem &= ~(1u << bc);
    selm |= (1 << bc);
  }

  // weights: softmax over approx scores of the selected 8, fold route weight
  float mx = -INFINITY;
#pragma unroll
  for (int j = 0; j < NCAND; ++j)
    if ((selm >> j) & 1) mx = fmaxf(mx, av[j]);
  float ew[NCAND]; float sum = 0.f;
#pragma unroll
  for (int j = 0; j < NCAND; ++j) {
    ew[j] = 0.f;
    if ((selm >> j) & 1) { ew[j] = expf(av[j] - mx); sum += ew[j]; }
  }
  if (lane == 0) {
    float rw = route_w[(size_t)row * 3 + level] / sum;
    size_t b8 = ((size_t)row * 3 + level) * TOPK;
    int k = 0;
#pragma unroll
    for (int j = 0; j < NCAND; ++j)
      if ((selm >> j) & 1) {
        sel_idx[b8 + k] = idx[j];
        sel_w[b8 + k]  = ew[j] * rw;
        ++k;
      }
  }
}

// ---------- final: out[row,:] = sum over 24 (level,k) of w * V16[level,idx,:] ----------
__global__ __launch_bounds__(128) void final_kernel(
    const _Float16* __restrict__ V16, const int* __restrict__ sel_idx,
    const float* __restrict__ sel_w, float* __restrict__ out) {
  __shared__ float wv[24];
  __shared__ int   widx[24];
  int row = blockIdx.x, t = threadIdx.x;   // t in [0,128): 8 halves each
  if (t < 24) {
    int l = t >> 3, j = t & 7;
    size_t base = ((size_t)row * 3 + l) * TOPK + j;
    wv[t]   = sel_w[base];
    widx[t] = l * SLOTS + sel_idx[base];
  }
  __syncthreads();
  float acc[8] = {0.f, 0.f, 0.f, 0.f, 0.f, 0.f, 0.f, 0.f};
  for (int i = 0; i < 24; ++i) {
    float w = wv[i];
    f16x8 v = *(const f16x8*)(V16 + (size_t)widx[i] * 1024 + t * 8);
#pragma unroll
    for (int e = 0; e < 8; ++e) acc[e] += w * (float)v[e];
  }
  float4* op = (float4*)(out + (size_t)row * 1024) + t * 2;
  op[0] = make_float4(acc[0], acc[1], acc[2], acc[3]);
  op[1] = make_float4(acc[4], acc[5], acc[6], acc[7]);
}

// ---------- launch ----------
extern "C" void kernel_launch(void* const* d_in, const int* in_sizes, int n_in,
                              void* d_out, int out_size, void* d_ws, size_t ws_size,
                              hipStream_t stream) {
  const float* q   = (const float*)d_in[0];
  const float* Ks  = (const float*)d_in[1];
  const float* Vs  = (const float*)d_in[2];
  const float* sal = (const float*)d_in[3];
  const float* W1  = (const float*)d_in[4];
  const float* b1  = (const float*)d_in[5];
  const float* W2  = (const float*)d_in[6];
  const float* b2  = (const float*)d_in[7];
  float* out = (float*)d_out;
  (void)in_sizes; (void)n_in; (void)out_size;

  char* p = (char*)d_ws;
  auto alloc = [&](size_t bytes) -> char* {
    char* r = p; p += (bytes + 255) & ~(size_t)255; return r;
  };
  // fixed (live across the whole pipeline)
  char*      q8    = alloc((size_t)BT * 1024);
  char*      K8    = alloc((size_t)LEVELS * SLOTS * 1024);
  _Float16*  V16   = (_Float16*)alloc((size_t)LEVELS * SLOTS * 1024 * 2);
  float*     route = (float*)alloc((size_t)BT * 3 * 4);
  int2*      cand2 = (int2*)alloc((size_t)BT * 3 * NCAND * 8);
  int*       s_idx = (int*)alloc((size_t)BT * 3 * TOPK * 4);
  float*     s_w   = (float*)alloc((size_t)BT * 3 * TOPK * 4);
  int*       hmask = (int*)alloc((size_t)BT * 3 * 4);
  size_t fixed = (size_t)(p - (char*)d_ws);

  // aliased region: router temps (dead before scores loop) overlap scores buffer
  char* ali = p;
  unsigned short* qh   = (unsigned short*)alloc((size_t)BT * 1024 * 2);
  unsigned short* W1Th = (unsigned short*)alloc((size_t)HDIM * 1024 * 2);
  unsigned short* W1Tl = (unsigned short*)alloc((size_t)HDIM * 1024 * 2);
  float*          h    = (float*)alloc((size_t)BT * HDIM * 4);
  size_t router_bytes = (size_t)(p - ali);

  unsigned short* scores = (unsigned short*)ali;   // fp16 [chunk][4096]
  int chunk = 2048;
  const int opts[4] = {16384, 8192, 4096, 2048};
  for (int i = 0; i < 4; ++i) {
    size_t scores_b = (size_t)opts[i] * SLOTS * 2;
    size_t need = fixed + (scores_b > router_bytes ? scores_b : router_bytes);
    if (need <= ws_size) { chunk = opts[i]; break; }
  }

  // 1) conversions
  conv_q8h_kernel<<<(BT * 1024 / 16) / 256, 256, 0, stream>>>(q, q8, qh);
  conv_i8_kernel<<<(LEVELS * SLOTS * 1024 / 16) / 256, 256, 0, stream>>>(Ks, K8, KSCALE);
  conv_v16_kernel<<<(LEVELS * SLOTS * 1024 / 8) / 256, 256, 0, stream>>>(Vs, V16);
  conv_w1t_kernel<<<(1024 * HDIM) / 256, 256, 0, stream>>>(W1, W1Th, W1Tl);

  // 2) router
  gemm_router_kernel<<<dim3(HDIM / 128, BT / 128), 256, 0, stream>>>(qh, W1Th, W1Tl, b1, h);
  router_head_kernel<<<BT / 4, 256, 0, stream>>>(h, W2, b2, route);

  // 3) per level, per chunk: i8 scores -> top-16 -> classify (easy done) -> hardmask rescore
  for (int level = 0; level < LEVELS; ++level) {
    const char*  K8L  = K8 + (size_t)level * SLOTS * 1024;
    const float* salL = sal + (size_t)level * SLOTS;
    const float* KsL  = Ks + (size_t)level * SLOTS * 1024;
    for (int c0 = 0; c0 < BT; c0 += chunk) {
      gemm_scores_i8_kernel<<<dim3(SLOTS / 128, chunk / 128), 256, 0, stream>>>(
          q8 + (size_t)c0 * 1024, K8L, salL, scores);
      select_kernel<<<chunk / 4, 256, 0, stream>>>(scores, cand2, c0, level);
      classify_kernel<<<chunk / 4, 256, 0, stream>>>(cand2, route, hmask,
                                                     s_idx, s_w, c0, level);
      rescore_kernel<<<chunk / 4, 256, 0, stream>>>(q, KsL, salL, route, cand2, hmask,
                                                    level, c0, s_idx, s_w);
    }
  }

  // 4) gather + weighted sum
  final_kernel<<<BT, 128, 0, stream>>>(V16, s_idx, s_w, out);
}